// Round 3
// baseline (554.933 us; speedup 1.0000x reference)
//
#include <hip/hip_runtime.h>
#include <math.h>

#define NROWS 200000
#define C 384
#define G 383
#define M 384          // G + 1
#define EPS 1e-5f
#define SQRTC 19.595917942265423f   // sqrt(384)

#define NBLK1 1024
#define THR1 512                    // 8 waves/block; 1024*8 = 8192 waves = 32/CU
#define NWAVES ((NBLK1 * THR1) / 64)
#define NBLKR 36                    // reduce blocks inside fused tail (36*256 = 9216)
#define NBLK4 576                   // fused tail grid (M*M/256)

// ---------------- workspace layout (floats) ----------------
#define WS_PART  0                              // NBLK1 * 1152  [block][cnt|sum|ss][384]
#define WS_S2    (WS_PART + NBLK1 * 1152)       // 8 * 1152 stage-2 partials
#define WS_PROTO (WS_S2 + 8 * 1152)             // 384
#define WS_STD   (WS_PROTO + 384)               // 384
#define WS_P3    (WS_STD + 384)                 // NBLK4 triple-sum partials
#define WS_CTR   (WS_P3 + NBLK4)                // 3 uint32: reduce-done | triple-done | proto-ready flag

// K1: one wave per row. float4 loads (16B/lane), register shuffle-reduce,
// 3 LDS atomics per ROW (lane 0 only), per-block plain-store flush.
// Also zeroes the three cross-kernel counters (ws is re-poisoned between
// iterations, so they must be re-armed every launch; stream order guarantees
// visibility before the tail kernel reads them).
__global__ __launch_bounds__(THR1) void stats_kernel(const float4* __restrict__ pred4,
                                                     const int* __restrict__ tgt,
                                                     float* __restrict__ ws,
                                                     int n_rows) {
    __shared__ float lc[384], ls[384], lq[384];
    const int tid = threadIdx.x;
    if (blockIdx.x == 0 && tid < 3) {
        unsigned int* ctr = (unsigned int*)(ws + WS_CTR);
        ctr[tid] = 0u;
    }
    for (int i = tid; i < 384; i += THR1) { lc[i] = 0.f; ls[i] = 0.f; lq[i] = 0.f; }
    __syncthreads();

    const int lane = tid & 63;
    const int wv   = (blockIdx.x * THR1 + tid) >> 6;

    for (int row = wv; row < n_rows; row += NWAVES) {
        const float4* rp = pred4 + (size_t)row * 96;   // 96 float4 chunks per row
        const int seg = tgt[row];                      // same-address broadcast load
        float4 v0 = rp[lane];
        float s = (v0.x + v0.y) + (v0.z + v0.w);
        float q = fmaf(v0.x, v0.x, fmaf(v0.y, v0.y, fmaf(v0.z, v0.z, v0.w * v0.w)));
        if (lane < 32) {
            float4 v1 = rp[64 + lane];
            s += (v1.x + v1.y) + (v1.z + v1.w);
            q += fmaf(v1.x, v1.x, fmaf(v1.y, v1.y, fmaf(v1.z, v1.z, v1.w * v1.w)));
        }
#pragma unroll
        for (int off = 32; off > 0; off >>= 1) {
            s += __shfl_down(s, off);
            q += __shfl_down(q, off);
        }
        if (lane == 0) {
            atomicAdd(&lc[seg], 1.0f);
            atomicAdd(&ls[seg], s);
            atomicAdd(&lq[seg], q);
        }
    }
    __syncthreads();

    float* dst = ws + (size_t)blockIdx.x * 1152;
    for (int i = tid; i < 384; i += THR1) {
        dst[i]       = lc[i];
        dst[384 + i] = ls[i];
        dst[768 + i] = lq[i];
    }
}

// K2 (fused tail): 576 blocks x 256 threads.
//  Phase A: blocks 0..35 reduce the 1024 partial vectors -> 8 stage-2 vectors
//    (identical (j,sub) mapping and summation order as before -> bit-identical);
//    the last of the 36 (counter ctr[0]) finalizes mean/std and release-stores
//    the ready flag ctr[2].
//  All 576 blocks acquire-spin on ctr[2] (576 blocks << 2048-block residency
//    capacity at 4 waves/block, so forward progress is guaranteed; spin lasts
//    ~3 us). Flag is poison-proof: a uniform fill leaves ctr[0] and ctr[2]
//    equal, so either both are 0 (logic runs normally) or the flag is nonzero
//    (spin exits immediately) — no hang in any replay scenario.
//  Phase B: triple sum with idx = a*M + x ('a' wave-uniform since M%64==0:
//    equal trip counts per lane, sp[b]/sst[b] wave-uniform broadcasts), then
//    last-block (ctr[1]) deterministic reduction of the 576 partials + write.
__global__ __launch_bounds__(256) void tail_kernel(float* __restrict__ ws,
                                                   float* __restrict__ out) {
    __shared__ float sp[M];
    __shared__ float sst[M];
    __shared__ float wsum[4];
    __shared__ int is_last;
    unsigned int* ctr = (unsigned int*)(ws + WS_CTR);
    const int tid = threadIdx.x;
    const int blk = blockIdx.x;

    if (blk < NBLKR) {
        const int t   = blk * 256 + tid;   // [0, 9216)
        const int j   = t % 1152;
        const int sub = t / 1152;          // [0, 8)
        float acc = 0.f;
#pragma unroll 8
        for (int b = sub; b < NBLK1; b += 8)
            acc += ws[WS_PART + (size_t)b * 1152 + j];
        ws[WS_S2 + sub * 1152 + j] = acc;

        __threadfence();                   // release this block's s2 stores
        __syncthreads();
        if (tid == 0)
            is_last = (atomicAdd(&ctr[0], 1u) == NBLKR - 1);
        __syncthreads();
        if (is_last) {
            __threadfence();               // acquire all s2 stores
            for (int g = tid; g < 384; g += 256) {
                float cnt_r = 0.f, sum = 0.f, ss = 0.f;
#pragma unroll
                for (int sub2 = 0; sub2 < 8; ++sub2) {
                    const float* s2 = ws + WS_S2 + sub2 * 1152;
                    cnt_r += s2[g];
                    sum   += s2[384 + g];
                    ss    += s2[768 + g];
                }
                float mean = 0.f, sd = 0.f;
                if (g < G && cnt_r > 0.5f) {
                    float cnt = cnt_r * (float)C;
                    mean = sum / cnt;
                    if (cnt_r > 1.5f) {
                        float cs    = ss - cnt * mean * mean;
                        float denom = fmaxf(cnt - 1.0f, 1.0f);
                        sd = sqrtf(fmaxf(cs / denom, 0.f));
                    }
                }
                ws[WS_PROTO + g] = mean;
                ws[WS_STD + g]   = sd;
            }
            __syncthreads();
            if (tid == 0) {
                __threadfence();           // release proto/std
                __hip_atomic_store(&ctr[2], 1u, __ATOMIC_RELEASE,
                                   __HIP_MEMORY_SCOPE_AGENT);
            }
        }
    }

    // grid-wide wait for proto/std
    if (tid == 0) {
        while (__hip_atomic_load(&ctr[2], __ATOMIC_ACQUIRE,
                                 __HIP_MEMORY_SCOPE_AGENT) == 0u) {
            __builtin_amdgcn_s_sleep(8);
        }
        __threadfence();                   // acquire proto/std into this block's view
    }
    __syncthreads();

    for (int i = tid; i < M; i += 256) {
        sp[i]  = ws[WS_PROTO + i];
        sst[i] = ws[WS_STD + i];
    }
    __syncthreads();

    const int idx = blk * 256 + tid;       // idx = a*M + x
    const int a   = idx / M;               // wave-uniform
    const int x   = idx - a * M;
    float partial = 0.f;
    {
        const float pa = sp[a];            // uniform
        const float sa = sst[a];           // uniform
        const float u  = fabsf(pa - sp[x]);       // per-lane
        const float tt = u / (u * SQRTC + EPS);   // |d[x,a]|
        const float tsa = tt * sa;
#pragma unroll 4
        for (int b = a + 1; b < M; ++b) {
            float nab = fabsf(sp[b] - pa) * SQRTC;    // wave-uniform
            float s   = fmaf(tt, sst[b], tsa);
            partial += s * __builtin_amdgcn_rcpf(nab + s + EPS);
        }
    }

#pragma unroll
    for (int off = 32; off > 0; off >>= 1)
        partial += __shfl_down(partial, off);
    if ((tid & 63) == 0) wsum[tid >> 6] = partial;
    __syncthreads();
    if (tid == 0) {
        ws[WS_P3 + blk] = wsum[0] + wsum[1] + wsum[2] + wsum[3];
        __threadfence();                   // release this block's partial
        is_last = (atomicAdd(&ctr[1], 1u) == NBLK4 - 1);
    }
    __syncthreads();
    if (!is_last) return;
    __threadfence();                        // acquire all 576 partials

    // deterministic final reduction of 576 partials with 256 threads
    float v = ws[WS_P3 + tid] + ws[WS_P3 + 256 + tid];
    if (tid < 64) v += ws[WS_P3 + 512 + tid];
#pragma unroll
    for (int off = 32; off > 0; off >>= 1)
        v += __shfl_down(v, off);
    __shared__ float fsum[4];
    if ((tid & 63) == 0) fsum[tid >> 6] = v;
    __syncthreads();
    if (tid == 0) {
        float acc = (fsum[0] + fsum[1]) + (fsum[2] + fsum[3]);
        out[0] = acc / ((float)M * (float)M * (float)M);
    }
}

extern "C" void kernel_launch(void* const* d_in, const int* in_sizes, int n_in,
                              void* d_out, int out_size, void* d_ws, size_t ws_size,
                              hipStream_t stream) {
    const float4* pred4 = (const float4*)d_in[0];
    const int*    tgt   = (const int*)d_in[1];
    float* ws  = (float*)d_ws;
    float* out = (float*)d_out;
    const int n_rows = in_sizes[1];

    stats_kernel<<<NBLK1, THR1, 0, stream>>>(pred4, tgt, ws, n_rows);
    tail_kernel<<<NBLK4, 256, 0, stream>>>(ws, out);
}

// Round 6
// 430.887 us; speedup vs baseline: 1.2879x; 1.2879x over previous
//
// IDLoss MI355X — v2-revert (r5 resubmit; identical semantics to Round-2 pass @431.4us)
#include <hip/hip_runtime.h>
#include <math.h>

#define NROWS 200000
#define C 384
#define G 383
#define M 384          // G + 1
#define EPS 1e-5f
#define SQRTC 19.595917942265423f   // sqrt(384)

#define NBLK1 1024
#define THR1 512                    // 8 waves/block; 1024*8 = 8192 waves = 32/CU
#define NWAVES ((NBLK1 * THR1) / 64)
#define NBLK2 24                    // reduce+finalize blocks (24 * 384 = 9216 threads)
#define NBLK4 576                   // triple-sum blocks (M*M/256)

// ---------------- workspace layout (floats) ----------------
#define WS_PART  0                              // NBLK1 * 1152  [block][cnt|sum|ss][384]
#define WS_S2    (WS_PART + NBLK1 * 1152)       // 8 * 1152 stage-2 partials
#define WS_PROTO (WS_S2 + 8 * 1152)             // 384
#define WS_STD   (WS_PROTO + 384)               // 384
#define WS_P3    (WS_STD + 384)                 // NBLK4 triple-sum partials
#define WS_CTR   (WS_P3 + NBLK4)                // 2 uint32 completion counters

// K1: one wave per row. float4 loads (16B/lane), register shuffle-reduce,
// 3 LDS atomics per ROW (lane 0 only), per-block plain-store flush.
// Also zeroes the two cross-kernel completion counters (ws is re-poisoned
// between iterations, so they must be re-armed every launch).
__global__ __launch_bounds__(THR1) void stats_kernel(const float4* __restrict__ pred4,
                                                     const int* __restrict__ tgt,
                                                     float* __restrict__ ws,
                                                     int n_rows) {
    __shared__ float lc[384], ls[384], lq[384];
    const int tid = threadIdx.x;
    if (blockIdx.x == 0 && tid == 0) {
        unsigned int* ctr = (unsigned int*)(ws + WS_CTR);
        ctr[0] = 0u;
        ctr[1] = 0u;
    }
    for (int i = tid; i < 384; i += THR1) { lc[i] = 0.f; ls[i] = 0.f; lq[i] = 0.f; }
    __syncthreads();

    const int lane = tid & 63;
    const int wv   = (blockIdx.x * THR1 + tid) >> 6;

    for (int row = wv; row < n_rows; row += NWAVES) {
        const float4* rp = pred4 + (size_t)row * 96;   // 96 float4 chunks per row
        const int seg = tgt[row];                      // same-address broadcast load
        float4 v0 = rp[lane];
        float s = (v0.x + v0.y) + (v0.z + v0.w);
        float q = fmaf(v0.x, v0.x, fmaf(v0.y, v0.y, fmaf(v0.z, v0.z, v0.w * v0.w)));
        if (lane < 32) {
            float4 v1 = rp[64 + lane];
            s += (v1.x + v1.y) + (v1.z + v1.w);
            q += fmaf(v1.x, v1.x, fmaf(v1.y, v1.y, fmaf(v1.z, v1.z, v1.w * v1.w)));
        }
#pragma unroll
        for (int off = 32; off > 0; off >>= 1) {
            s += __shfl_down(s, off);
            q += __shfl_down(q, off);
        }
        if (lane == 0) {
            atomicAdd(&lc[seg], 1.0f);
            atomicAdd(&ls[seg], s);
            atomicAdd(&lq[seg], q);
        }
    }
    __syncthreads();

    float* dst = ws + (size_t)blockIdx.x * 1152;
    for (int i = tid; i < 384; i += THR1) {
        dst[i]       = lc[i];
        dst[384 + i] = ls[i];
        dst[768 + i] = lq[i];
    }
}

// K2: reduce NBLK1 partial vectors -> 8 stage-2 vectors, then the LAST block
// (device-atomic completion counter) finalizes mean/std per group.
// Stage-2 values and the finalize arithmetic are bit-identical to the previous
// separate-kernel version (same (j,sub) mapping, same summation order).
__global__ __launch_bounds__(384) void reduce_finalize_kernel(float* __restrict__ ws) {
    __shared__ int is_last;
    const int t   = blockIdx.x * 384 + threadIdx.x;   // [0, 9216)
    const int j   = t % 1152;
    const int sub = t / 1152;                          // [0, 8)
    float acc = 0.f;
#pragma unroll 8
    for (int b = sub; b < NBLK1; b += 8)
        acc += ws[WS_PART + (size_t)b * 1152 + j];
    ws[WS_S2 + sub * 1152 + j] = acc;

    __threadfence();                 // release: make this block's s2 stores visible
    __syncthreads();
    if (threadIdx.x == 0) {
        unsigned int* ctr = (unsigned int*)(ws + WS_CTR);
        is_last = (atomicAdd(&ctr[0], 1u) == NBLK2 - 1);
    }
    __syncthreads();
    if (!is_last) return;
    __threadfence();                 // acquire: see all other blocks' s2 stores

    const int g = threadIdx.x;       // 384 threads
    float cnt_r = 0.f, sum = 0.f, ss = 0.f;
#pragma unroll
    for (int sub2 = 0; sub2 < 8; ++sub2) {
        const float* s2 = ws + WS_S2 + sub2 * 1152;
        cnt_r += s2[g];
        sum   += s2[384 + g];
        ss    += s2[768 + g];
    }
    float mean = 0.f, sd = 0.f;
    if (g < G && cnt_r > 0.5f) {
        float cnt = cnt_r * (float)C;
        mean = sum / cnt;
        if (cnt_r > 1.5f) {
            float cs    = ss - cnt * mean * mean;
            float denom = fmaxf(cnt - 1.0f, 1.0f);
            sd = sqrtf(fmaxf(cs / denom, 0.f));
        }
    }
    ws[WS_PROTO + g] = mean;
    ws[WS_STD + g]   = sd;
}

// K3: triple sum + final write fused. Mapping idx = a*M + x: since M is a
// multiple of 64, 'a' is wave-uniform -> every lane in a wave runs exactly
// (M-1-a) iterations (zero within-wave idle work), and sp[b]/sst[b] loads are
// wave-uniform broadcasts. Per-lane sp[x] reads are consecutive (free 2-way
// bank alias). Lanes with u==0 contribute exact zeros, so no guard needed.
// The LAST block (completion counter) reduces the 576 block partials in a
// fixed deterministic order and writes the scalar output.
__global__ __launch_bounds__(256) void triple_write_kernel(float* __restrict__ ws,
                                                           float* __restrict__ out) {
    __shared__ float sp[M];
    __shared__ float sst[M];
    __shared__ float wsum[4];
    __shared__ int is_last;
    const int tid = threadIdx.x;

    for (int i = tid; i < M; i += 256) {
        sp[i]  = ws[WS_PROTO + i];
        sst[i] = ws[WS_STD + i];
    }
    __syncthreads();

    const int idx = blockIdx.x * 256 + tid;   // idx = a*M + x
    const int a   = idx / M;                  // wave-uniform
    const int x   = idx - a * M;
    float partial = 0.f;
    {
        const float pa = sp[a];               // uniform
        const float sa = sst[a];              // uniform
        const float u  = fabsf(pa - sp[x]);   // per-lane
        const float tt = u / (u * SQRTC + EPS);   // |d[x,a]|
        const float tsa = tt * sa;
#pragma unroll 4
        for (int b = a + 1; b < M; ++b) {
            float nab = fabsf(sp[b] - pa) * SQRTC;    // wave-uniform
            float s   = fmaf(tt, sst[b], tsa);
            partial += s * __builtin_amdgcn_rcpf(nab + s + EPS);
        }
    }

#pragma unroll
    for (int off = 32; off > 0; off >>= 1)
        partial += __shfl_down(partial, off);
    if ((tid & 63) == 0) wsum[tid >> 6] = partial;
    __syncthreads();
    if (tid == 0) {
        ws[WS_P3 + blockIdx.x] = wsum[0] + wsum[1] + wsum[2] + wsum[3];
        __threadfence();                     // release this block's partial
        unsigned int* ctr = (unsigned int*)(ws + WS_CTR);
        is_last = (atomicAdd(&ctr[1], 1u) == NBLK4 - 1);
    }
    __syncthreads();
    if (!is_last) return;
    __threadfence();                          // acquire all 576 partials

    // deterministic final reduction of 576 partials with 256 threads
    float v = ws[WS_P3 + tid] + ws[WS_P3 + 256 + tid];
    if (tid < 64) v += ws[WS_P3 + 512 + tid];
#pragma unroll
    for (int off = 32; off > 0; off >>= 1)
        v += __shfl_down(v, off);
    __shared__ float fsum[4];
    if ((tid & 63) == 0) fsum[tid >> 6] = v;
    __syncthreads();
    if (tid == 0) {
        float acc = (fsum[0] + fsum[1]) + (fsum[2] + fsum[3]);
        out[0] = acc / ((float)M * (float)M * (float)M);
    }
}

extern "C" void kernel_launch(void* const* d_in, const int* in_sizes, int n_in,
                              void* d_out, int out_size, void* d_ws, size_t ws_size,
                              hipStream_t stream) {
    const float4* pred4 = (const float4*)d_in[0];
    const int*    tgt   = (const int*)d_in[1];
    float* ws  = (float*)d_ws;
    float* out = (float*)d_out;
    const int n_rows = in_sizes[1];

    stats_kernel<<<NBLK1, THR1, 0, stream>>>(pred4, tgt, ws, n_rows);
    reduce_finalize_kernel<<<NBLK2, 384, 0, stream>>>(ws);
    triple_write_kernel<<<NBLK4, 256, 0, stream>>>(ws, out);
}